// Round 1
// baseline (1403.583 us; speedup 1.0000x reference)
//
#include <hip/hip_runtime.h>
#include <hip/hip_bf16.h>

#define B_ 4
#define N_ 2048
#define C_ 256
#define H_ 8
#define D_ 32
#define M_TOT (B_ * N_)   // 8192

// ---------------------------------------------------------------------------
// Kernel 1: QKV projection. Y = x @ W_qkv + b_qkv, scattered to q/k/v buffers
// laid out [B,H,N,D]. x:[8192,256], W:[256,768].
// 64x64 output tile per block, 256 threads, 4x4 micro-tile, BK=64.
// ---------------------------------------------------------------------------
__global__ __launch_bounds__(256) void qkv_gemm(const float* __restrict__ x,
                                                const float* __restrict__ W,
                                                const float* __restrict__ bias,
                                                float* __restrict__ qb,
                                                float* __restrict__ kb,
                                                float* __restrict__ vb) {
    __shared__ float xs[64][68];
    __shared__ float ws[64][68];
    const int t = threadIdx.x;
    const int tx = t & 15, ty = t >> 4;
    const int m0 = blockIdx.y * 64;
    const int j0 = blockIdx.x * 64;
    float acc[4][4] = {};
    for (int k0 = 0; k0 < 256; k0 += 64) {
#pragma unroll
        for (int rep = 0; rep < 4; ++rep) {
            const int row = ty + rep * 16;
            const int c4 = tx * 4;
            *(float4*)&xs[row][c4] =
                *(const float4*)&x[(size_t)(m0 + row) * 256 + k0 + c4];
            *(float4*)&ws[row][c4] =
                *(const float4*)&W[(size_t)(k0 + row) * 768 + j0 + c4];
        }
        __syncthreads();
#pragma unroll
        for (int kk = 0; kk < 64; kk += 4) {
            float4 a[4], b[4];
#pragma unroll
            for (int ii = 0; ii < 4; ++ii) a[ii] = *(float4*)&xs[ty * 4 + ii][kk];
#pragma unroll
            for (int kx = 0; kx < 4; ++kx) b[kx] = *(float4*)&ws[kk + kx][tx * 4];
#pragma unroll
            for (int ii = 0; ii < 4; ++ii) {
                const float av[4] = {a[ii].x, a[ii].y, a[ii].z, a[ii].w};
#pragma unroll
                for (int kx = 0; kx < 4; ++kx) {
                    acc[ii][0] = fmaf(av[kx], b[kx].x, acc[ii][0]);
                    acc[ii][1] = fmaf(av[kx], b[kx].y, acc[ii][1]);
                    acc[ii][2] = fmaf(av[kx], b[kx].z, acc[ii][2]);
                    acc[ii][3] = fmaf(av[kx], b[kx].w, acc[ii][3]);
                }
            }
        }
        __syncthreads();
    }
#pragma unroll
    for (int ii = 0; ii < 4; ++ii) {
        const int gm = m0 + ty * 4 + ii;
        const int bb = gm >> 11, n = gm & 2047;
#pragma unroll
        for (int jj = 0; jj < 4; ++jj) {
            const int c = j0 + tx * 4 + jj;
            const float val = acc[ii][jj] + bias[c];
            const int t3 = c >> 8, rem = c & 255;
            const int h = rem >> 5, dd = rem & 31;
            float* dst = (t3 == 0) ? qb : (t3 == 1) ? kb : vb;
            dst[((size_t)(bb * H_ + h) * N_ + n) * D_ + dd] = val;
        }
    }
}

// ---------------------------------------------------------------------------
// Kernel 2: flash attention (fp32 VALU). One block = 8 query rows of one
// (b,h); 32 lanes per row. Online softmax over m-tiles of 32.
// attn = softmax(q.kT * scale * (0.1+0.9*mask)) ; out = attn @ v
// Output written [B,N,H*D] so the final projection is a plain GEMM.
// ---------------------------------------------------------------------------
__global__ __launch_bounds__(256) void attn_kernel(const float* __restrict__ qb,
                                                   const float* __restrict__ kb,
                                                   const float* __restrict__ vb,
                                                   const float* __restrict__ mask,
                                                   float* __restrict__ ao) {
    __shared__ float kT[32][36];
    __shared__ float vT[32][36];
    const int t = threadIdx.x;
    const int r = t >> 5, l = t & 31;
    const int bh = blockIdx.x >> 8;   // 0..31
    const int rb = blockIdx.x & 255;  // row block within N
    const int n = rb * 8 + r;
    const size_t qoff = ((size_t)bh * N_ + n) * D_;

    float qr[32];
#pragma unroll
    for (int d4 = 0; d4 < 8; ++d4) {
        const float4 v4 = *(const float4*)&qb[qoff + d4 * 4];
        qr[d4 * 4 + 0] = v4.x;
        qr[d4 * 4 + 1] = v4.y;
        qr[d4 * 4 + 2] = v4.z;
        qr[d4 * 4 + 3] = v4.w;
    }

    float acc = 0.f, m_run = -__builtin_inff(), l_run = 0.f;
    const float scale = 0.17677669529663687f;  // 32^-0.5

    for (int m0 = 0; m0 < N_; m0 += 32) {
        {
            const int kk = t >> 3;        // 0..31
            const int f4 = (t & 7) * 4;   // 0,4,...,28
            const size_t g = ((size_t)bh * N_ + m0 + kk) * D_ + f4;
            *(float4*)&kT[kk][f4] = *(const float4*)&kb[g];
            *(float4*)&vT[kk][f4] = *(const float4*)&vb[g];
        }
        __syncthreads();

        float s = 0.f;
#pragma unroll
        for (int d4 = 0; d4 < 8; ++d4) {
            const float4 kv = *(float4*)&kT[l][d4 * 4];
            s = fmaf(qr[d4 * 4 + 0], kv.x, s);
            s = fmaf(qr[d4 * 4 + 1], kv.y, s);
            s = fmaf(qr[d4 * 4 + 2], kv.z, s);
            s = fmaf(qr[d4 * 4 + 3], kv.w, s);
        }
        const float mv = mask[(size_t)n * N_ + m0 + l];
        s = s * scale * (0.1f + 0.9f * mv);

        float red = s;
#pragma unroll
        for (int off = 16; off >= 1; off >>= 1)
            red = fmaxf(red, __shfl_xor(red, off, 32));
        const float m_new = fmaxf(m_run, red);
        const float corr = __expf(m_run - m_new);
        const float p = __expf(s - m_new);
        float ps = p;
#pragma unroll
        for (int off = 16; off >= 1; off >>= 1) ps += __shfl_xor(ps, off, 32);
        l_run = l_run * corr + ps;
        m_run = m_new;
        acc *= corr;
#pragma unroll
        for (int m = 0; m < 32; ++m) {
            const float pm = __shfl(p, m, 32);
            acc = fmaf(pm, vT[m][l], acc);
        }
        __syncthreads();
    }
    const float o = acc / l_run;
    const int bb = bh >> 3, h = bh & 7;
    ao[((size_t)bb * N_ + n) * C_ + h * D_ + l] = o;
}

// ---------------------------------------------------------------------------
// Kernel 3: output projection. out = ao @ W_out + b_out. [8192,256]x[256,256]
// ---------------------------------------------------------------------------
__global__ __launch_bounds__(256) void out_gemm(const float* __restrict__ xin,
                                                const float* __restrict__ W,
                                                const float* __restrict__ bias,
                                                float* __restrict__ out) {
    __shared__ float xs[64][68];
    __shared__ float ws[64][68];
    const int t = threadIdx.x;
    const int tx = t & 15, ty = t >> 4;
    const int m0 = blockIdx.y * 64;
    const int j0 = blockIdx.x * 64;
    float acc[4][4] = {};
    for (int k0 = 0; k0 < 256; k0 += 64) {
#pragma unroll
        for (int rep = 0; rep < 4; ++rep) {
            const int row = ty + rep * 16;
            const int c4 = tx * 4;
            *(float4*)&xs[row][c4] =
                *(const float4*)&xin[(size_t)(m0 + row) * 256 + k0 + c4];
            *(float4*)&ws[row][c4] =
                *(const float4*)&W[(size_t)(k0 + row) * 256 + j0 + c4];
        }
        __syncthreads();
#pragma unroll
        for (int kk = 0; kk < 64; kk += 4) {
            float4 a[4], b[4];
#pragma unroll
            for (int ii = 0; ii < 4; ++ii) a[ii] = *(float4*)&xs[ty * 4 + ii][kk];
#pragma unroll
            for (int kx = 0; kx < 4; ++kx) b[kx] = *(float4*)&ws[kk + kx][tx * 4];
#pragma unroll
            for (int ii = 0; ii < 4; ++ii) {
                const float av[4] = {a[ii].x, a[ii].y, a[ii].z, a[ii].w};
#pragma unroll
                for (int kx = 0; kx < 4; ++kx) {
                    acc[ii][0] = fmaf(av[kx], b[kx].x, acc[ii][0]);
                    acc[ii][1] = fmaf(av[kx], b[kx].y, acc[ii][1]);
                    acc[ii][2] = fmaf(av[kx], b[kx].z, acc[ii][2]);
                    acc[ii][3] = fmaf(av[kx], b[kx].w, acc[ii][3]);
                }
            }
        }
        __syncthreads();
    }
#pragma unroll
    for (int ii = 0; ii < 4; ++ii) {
        const int gm = m0 + ty * 4 + ii;
#pragma unroll
        for (int jj = 0; jj < 4; ++jj) {
            const int c = j0 + tx * 4 + jj;
            out[(size_t)gm * 256 + c] = acc[ii][jj] + bias[c];
        }
    }
}

extern "C" void kernel_launch(void* const* d_in, const int* in_sizes, int n_in,
                              void* d_out, int out_size, void* d_ws, size_t ws_size,
                              hipStream_t stream) {
    const float* x = (const float*)d_in[0];
    const float* mask = (const float*)d_in[1];
    const float* W_qkv = (const float*)d_in[2];
    const float* b_qkv = (const float*)d_in[3];
    const float* W_out = (const float*)d_in[4];
    const float* b_out = (const float*)d_in[5];
    float* out = (float*)d_out;

    const size_t per = (size_t)B_ * H_ * N_ * D_;  // 2,097,152 floats
    float* qb = (float*)d_ws;
    float* kb = qb + per;
    float* vb = kb + per;
    float* ao = vb + per;

    // 1) QKV projection
    qkv_gemm<<<dim3(12, 128), 256, 0, stream>>>(x, W_qkv, b_qkv, qb, kb, vb);
    // 2) attention
    attn_kernel<<<dim3(B_ * H_ * (N_ / 8)), 256, 0, stream>>>(qb, kb, vb, mask, ao);
    // 3) output projection
    out_gemm<<<dim3(4, 128), 256, 0, stream>>>(ao, W_out, b_out, out);
}

// Round 2
// 274.021 us; speedup vs baseline: 5.1222x; 5.1222x over previous
//
#include <hip/hip_runtime.h>
#include <hip/hip_bf16.h>

#define B_ 4
#define N_ 2048
#define C_ 256
#define H_ 8
#define D_ 32

typedef __attribute__((ext_vector_type(4))) short bf16x4;
typedef __attribute__((ext_vector_type(8))) short bf16x8;
typedef __attribute__((ext_vector_type(8))) short s16x8;
typedef __attribute__((ext_vector_type(16))) float f32x16;

static __device__ __forceinline__ float b2f(short u) {
    unsigned v = ((unsigned)(unsigned short)u) << 16;
    return __builtin_bit_cast(float, v);
}
static __device__ __forceinline__ short f2bs(float f) {
    __hip_bfloat16 h = __float2bfloat16(f);
    return __builtin_bit_cast(short, h);
}

// ---------------------------------------------------------------------------
// mask factor transpose: maskT[m][n] = bf16( scale * (0.1 + 0.9*mask[n][m]) )
// ---------------------------------------------------------------------------
__global__ __launch_bounds__(256) void mask_transpose(const float* __restrict__ mask,
                                                      short* __restrict__ maskT) {
    __shared__ float tl[32][33];
    const int t = threadIdx.x;
    const int c = t & 31, r0 = t >> 5;
    const int n0 = blockIdx.y * 32, m0 = blockIdx.x * 32;
#pragma unroll
    for (int rr = r0; rr < 32; rr += 8)
        tl[rr][c] = mask[(size_t)(n0 + rr) * N_ + m0 + c];
    __syncthreads();
    const float sc = 0.17677669529663687f;
#pragma unroll
    for (int rr = r0; rr < 32; rr += 8) {
        const float v = tl[c][rr];
        maskT[(size_t)(m0 + rr) * N_ + n0 + c] = f2bs(sc * (0.1f + 0.9f * v));
    }
}

// ---------------------------------------------------------------------------
// Kernel 1: QKV projection (fp32 compute), writes bf16 q/k/v in [B,H,N,D].
// ---------------------------------------------------------------------------
__global__ __launch_bounds__(256) void qkv_gemm(const float* __restrict__ x,
                                                const float* __restrict__ W,
                                                const float* __restrict__ bias,
                                                __hip_bfloat16* __restrict__ qb,
                                                __hip_bfloat16* __restrict__ kb,
                                                __hip_bfloat16* __restrict__ vb) {
    __shared__ float xs[64][68];
    __shared__ float ws[64][68];
    const int t = threadIdx.x;
    const int tx = t & 15, ty = t >> 4;
    const int m0 = blockIdx.y * 64;
    const int j0 = blockIdx.x * 64;
    float acc[4][4] = {};
    for (int k0 = 0; k0 < 256; k0 += 64) {
#pragma unroll
        for (int rep = 0; rep < 4; ++rep) {
            const int row = ty + rep * 16;
            const int c4 = tx * 4;
            *(float4*)&xs[row][c4] =
                *(const float4*)&x[(size_t)(m0 + row) * 256 + k0 + c4];
            *(float4*)&ws[row][c4] =
                *(const float4*)&W[(size_t)(k0 + row) * 768 + j0 + c4];
        }
        __syncthreads();
#pragma unroll
        for (int kk = 0; kk < 64; kk += 4) {
            float4 a[4], b[4];
#pragma unroll
            for (int ii = 0; ii < 4; ++ii) a[ii] = *(float4*)&xs[ty * 4 + ii][kk];
#pragma unroll
            for (int kx = 0; kx < 4; ++kx) b[kx] = *(float4*)&ws[kk + kx][tx * 4];
#pragma unroll
            for (int ii = 0; ii < 4; ++ii) {
                const float av[4] = {a[ii].x, a[ii].y, a[ii].z, a[ii].w};
#pragma unroll
                for (int kx = 0; kx < 4; ++kx) {
                    acc[ii][0] = fmaf(av[kx], b[kx].x, acc[ii][0]);
                    acc[ii][1] = fmaf(av[kx], b[kx].y, acc[ii][1]);
                    acc[ii][2] = fmaf(av[kx], b[kx].z, acc[ii][2]);
                    acc[ii][3] = fmaf(av[kx], b[kx].w, acc[ii][3]);
                }
            }
        }
        __syncthreads();
    }
#pragma unroll
    for (int ii = 0; ii < 4; ++ii) {
        const int gm = m0 + ty * 4 + ii;
        const int bb = gm >> 11, n = gm & 2047;
#pragma unroll
        for (int jj = 0; jj < 4; ++jj) {
            const int c = j0 + tx * 4 + jj;
            const float val = acc[ii][jj] + bias[c];
            const int t3 = c >> 8, rem = c & 255;
            const int h = rem >> 5, dd = rem & 31;
            __hip_bfloat16* dst = (t3 == 0) ? qb : (t3 == 1) ? kb : vb;
            dst[((size_t)(bb * H_ + h) * N_ + n) * D_ + dd] = __float2bfloat16(val);
        }
    }
}

// ---------------------------------------------------------------------------
// Kernel 2: MFMA flash attention.
// Block = 4 waves x 32 q-rows (128 rows), one (b,h). KV tiles of 64.
// S^T = K.Q^T via mfma_32x32x16; P^T stays in regs as the B-fragment of
// out^T = V^T.P^T. No max-subtraction (scores bounded by construction).
// ---------------------------------------------------------------------------
__global__ __launch_bounds__(256) void attn_mfma(const short* __restrict__ qb,
                                                 const short* __restrict__ kb,
                                                 const short* __restrict__ vb,
                                                 const short* __restrict__ maskT,
                                                 float* __restrict__ ao) {
    __shared__ short Kl[64 * 36];
    __shared__ short Vt[32 * 68];
    __shared__ float Ow[4][32 * 33];
    const int t = threadIdx.x;
    const int w = t >> 6, lane = t & 63, l5 = lane & 31, hi = lane >> 5;
    const int hi4 = hi * 4;
    const int bh = blockIdx.x >> 4, qt = blockIdx.x & 15;
    const int q0w = qt * 128 + w * 32;
    const int nq = q0w + l5;

    // Q B-fragments (per-lane rows q=l5), loaded once.
    const short* qrow = qb + ((size_t)bh * N_ + nq) * D_;
    const bf16x8 qf0 = __builtin_shufflevector(*(const bf16x4*)(qrow + hi4),
                                               *(const bf16x4*)(qrow + hi4 + 8),
                                               0, 1, 2, 3, 4, 5, 6, 7);
    const bf16x8 qf1 = __builtin_shufflevector(*(const bf16x4*)(qrow + hi4 + 16),
                                               *(const bf16x4*)(qrow + hi4 + 24),
                                               0, 1, 2, 3, 4, 5, 6, 7);
    f32x16 acc;
#pragma unroll
    for (int i = 0; i < 16; ++i) acc[i] = 0.f;
    float lsum = 0.f;

    const int srow = t >> 2, sch = t & 3;
    const size_t kvbase = (size_t)bh * N_ * D_;

    for (int m0 = 0; m0 < N_; m0 += 64) {
        __syncthreads();
        {   // stage K [64][32] row-major and V^T [32][64] into LDS (bf16)
            const size_t g = kvbase + (size_t)(m0 + srow) * D_ + sch * 8;
            const s16x8 k8 = *(const s16x8*)(kb + g);
            const s16x8 v8 = *(const s16x8*)(vb + g);
            *(bf16x4*)&Kl[srow * 36 + sch * 8] =
                __builtin_shufflevector(k8, k8, 0, 1, 2, 3);
            *(bf16x4*)&Kl[srow * 36 + sch * 8 + 4] =
                __builtin_shufflevector(k8, k8, 4, 5, 6, 7);
#pragma unroll
            for (int j = 0; j < 8; ++j)
                Vt[(sch * 8 + j) * 68 + srow] = v8[j];
        }
        __syncthreads();
#pragma unroll
        for (int tile = 0; tile < 2; ++tile) {
            // S^T tile (m = m0+tile*32 .. +31  x  q = q0w..q0w+31)
            const short* kr = &Kl[(tile * 32 + l5) * 36];
            const bf16x8 af0 = __builtin_shufflevector(*(const bf16x4*)(kr + hi4),
                                                       *(const bf16x4*)(kr + hi4 + 8),
                                                       0, 1, 2, 3, 4, 5, 6, 7);
            const bf16x8 af1 = __builtin_shufflevector(*(const bf16x4*)(kr + hi4 + 16),
                                                       *(const bf16x4*)(kr + hi4 + 24),
                                                       0, 1, 2, 3, 4, 5, 6, 7);
            f32x16 s;
#pragma unroll
            for (int i = 0; i < 16; ++i) s[i] = 0.f;
            s = __builtin_amdgcn_mfma_f32_32x32x16_bf16(af0, qf0, s, 0, 0, 0);
            s = __builtin_amdgcn_mfma_f32_32x32x16_bf16(af1, qf1, s, 0, 0, 0);
            // p = exp(s * premultiplied mask factor); no max subtraction
            const short* mrow = maskT + (size_t)(m0 + tile * 32 + hi4) * N_ + nq;
            float p[16];
#pragma unroll
            for (int r = 0; r < 16; ++r) {
                const float fm = b2f(mrow[((r & 3) + 8 * (r >> 2)) * N_]);
                p[r] = __expf(s[r] * fm);
                lsum += p[r];
            }
            // P^T C-regs in order == B-fragment of PV (verified C layout)
            bf16x8 pf0, pf1;
#pragma unroll
            for (int j = 0; j < 8; ++j) {
                pf0[j] = f2bs(p[j]);
                pf1[j] = f2bs(p[8 + j]);
            }
            // out^T += V^T . P^T  (two k=16 steps per 32-m tile)
            const short* vr = &Vt[l5 * 68 + tile * 32];
            const bf16x8 vf0 = __builtin_shufflevector(*(const bf16x4*)(vr + hi4),
                                                       *(const bf16x4*)(vr + hi4 + 8),
                                                       0, 1, 2, 3, 4, 5, 6, 7);
            const bf16x8 vf1 = __builtin_shufflevector(*(const bf16x4*)(vr + 16 + hi4),
                                                       *(const bf16x4*)(vr + 16 + hi4 + 8),
                                                       0, 1, 2, 3, 4, 5, 6, 7);
            acc = __builtin_amdgcn_mfma_f32_32x32x16_bf16(vf0, pf0, acc, 0, 0, 0);
            acc = __builtin_amdgcn_mfma_f32_32x32x16_bf16(vf1, pf1, acc, 0, 0, 0);
        }
    }
    // row sum: q-row l5 lives in lanes (l5, l5+32)
    const float lt = lsum + __shfl_xor(lsum, 32);
    const float inv = 1.0f / lt;
    float* ow = Ow[w];
    __syncthreads();
#pragma unroll
    for (int r = 0; r < 16; ++r) {
        const int d = (r & 3) + 8 * (r >> 2) + hi4;
        ow[d * 33 + l5] = acc[r] * inv;
    }
    __syncthreads();
    const int bb = bh >> 3, h = bh & 7;
    float* orow = ao + (size_t)(bb * N_ + nq) * C_ + h * D_ + hi * 16;
#pragma unroll
    for (int j4 = 0; j4 < 4; ++j4) {
        float4 v4;
        v4.x = ow[(hi * 16 + j4 * 4 + 0) * 33 + l5];
        v4.y = ow[(hi * 16 + j4 * 4 + 1) * 33 + l5];
        v4.z = ow[(hi * 16 + j4 * 4 + 2) * 33 + l5];
        v4.w = ow[(hi * 16 + j4 * 4 + 3) * 33 + l5];
        *(float4*)(orow + j4 * 4) = v4;
    }
}

// ---------------------------------------------------------------------------
// Kernel 3: output projection (fp32). out = ao @ W_out + b_out.
// ---------------------------------------------------------------------------
__global__ __launch_bounds__(256) void out_gemm(const float* __restrict__ xin,
                                                const float* __restrict__ W,
                                                const float* __restrict__ bias,
                                                float* __restrict__ out) {
    __shared__ float xs[64][68];
    __shared__ float ws[64][68];
    const int t = threadIdx.x;
    const int tx = t & 15, ty = t >> 4;
    const int m0 = blockIdx.y * 64;
    const int j0 = blockIdx.x * 64;
    float acc[4][4] = {};
    for (int k0 = 0; k0 < 256; k0 += 64) {
#pragma unroll
        for (int rep = 0; rep < 4; ++rep) {
            const int row = ty + rep * 16;
            const int c4 = tx * 4;
            *(float4*)&xs[row][c4] =
                *(const float4*)&xin[(size_t)(m0 + row) * 256 + k0 + c4];
            *(float4*)&ws[row][c4] =
                *(const float4*)&W[(size_t)(k0 + row) * 256 + j0 + c4];
        }
        __syncthreads();
#pragma unroll
        for (int kk = 0; kk < 64; kk += 4) {
            float4 a[4], b[4];
#pragma unroll
            for (int ii = 0; ii < 4; ++ii) a[ii] = *(float4*)&xs[ty * 4 + ii][kk];
#pragma unroll
            for (int kx = 0; kx < 4; ++kx) b[kx] = *(float4*)&ws[kk + kx][tx * 4];
#pragma unroll
            for (int ii = 0; ii < 4; ++ii) {
                const float av[4] = {a[ii].x, a[ii].y, a[ii].z, a[ii].w};
#pragma unroll
                for (int kx = 0; kx < 4; ++kx) {
                    acc[ii][0] = fmaf(av[kx], b[kx].x, acc[ii][0]);
                    acc[ii][1] = fmaf(av[kx], b[kx].y, acc[ii][1]);
                    acc[ii][2] = fmaf(av[kx], b[kx].z, acc[ii][2]);
                    acc[ii][3] = fmaf(av[kx], b[kx].w, acc[ii][3]);
                }
            }
        }
        __syncthreads();
    }
#pragma unroll
    for (int ii = 0; ii < 4; ++ii) {
        const int gm = m0 + ty * 4 + ii;
#pragma unroll
        for (int jj = 0; jj < 4; ++jj) {
            const int c = j0 + tx * 4 + jj;
            out[(size_t)gm * 256 + c] = acc[ii][jj] + bias[c];
        }
    }
}

extern "C" void kernel_launch(void* const* d_in, const int* in_sizes, int n_in,
                              void* d_out, int out_size, void* d_ws, size_t ws_size,
                              hipStream_t stream) {
    const float* x = (const float*)d_in[0];
    const float* mask = (const float*)d_in[1];
    const float* W_qkv = (const float*)d_in[2];
    const float* b_qkv = (const float*)d_in[3];
    const float* W_out = (const float*)d_in[4];
    const float* b_out = (const float*)d_in[5];
    float* out = (float*)d_out;

    const size_t per = (size_t)B_ * H_ * N_ * D_;  // 2,097,152
    short* qb = (short*)d_ws;
    short* kb = qb + per;
    short* vb = kb + per;
    short* maskT = vb + per;                       // 4,194,304 elems
    float* ao = (float*)(maskT + (size_t)N_ * N_); // 2,097,152 floats

    mask_transpose<<<dim3(64, 64), 256, 0, stream>>>(mask, maskT);
    qkv_gemm<<<dim3(12, 128), 256, 0, stream>>>(x, W_qkv, b_qkv,
                                                (__hip_bfloat16*)qb,
                                                (__hip_bfloat16*)kb,
                                                (__hip_bfloat16*)vb);
    attn_mfma<<<dim3(512), 256, 0, stream>>>(qb, kb, vb, maskT, ao);
    out_gemm<<<dim3(4, 128), 256, 0, stream>>>(ao, W_out, b_out, out);
}

// Round 3
// 130.146 us; speedup vs baseline: 10.7847x; 2.1055x over previous
//
#include <hip/hip_runtime.h>
#include <hip/hip_bf16.h>

#define B_ 4
#define N_ 2048
#define C_ 256
#define H_ 8
#define D_ 32

typedef __attribute__((ext_vector_type(4))) short bf16x4;
typedef __attribute__((ext_vector_type(8))) short bf16x8;
typedef __attribute__((ext_vector_type(16))) float f32x16;

static __device__ __forceinline__ float b2f(short u) {
    unsigned v = ((unsigned)(unsigned short)u) << 16;
    return __builtin_bit_cast(float, v);
}
static __device__ __forceinline__ short f2bs(float f) {
    __hip_bfloat16 h = __float2bfloat16(f);
    return __builtin_bit_cast(short, h);
}

// ---------------------------------------------------------------------------
// mask relayout into MFMA C-fragment order, premultiplied:
// maskF[((mt*2+hi)*N + n)*16 + r] = bf16( scale*log2e*(0.1+0.9*mask[n][mt*32+crow]) )
// crow(r,hi) = (r&3) + 8*(r>>2) + 4*hi  (verified 32x32 C layout)
// ---------------------------------------------------------------------------
__global__ __launch_bounds__(256) void mask_relayout(const float* __restrict__ mask,
                                                     short* __restrict__ maskF) {
    const int t = threadIdx.x;
    const int n = blockIdx.y * 64 + (t & 63);
    const int mt = blockIdx.x * 4 + (t >> 6);
    const float cf = 0.17677669529663687f * 1.4426950408889634f;  // D^-.5 * log2(e)
    float v[32];
    const float4* src = (const float4*)(mask + (size_t)n * N_ + mt * 32);
#pragma unroll
    for (int i = 0; i < 8; ++i) {
        const float4 f4 = src[i];
        v[i * 4 + 0] = f4.x; v[i * 4 + 1] = f4.y;
        v[i * 4 + 2] = f4.z; v[i * 4 + 3] = f4.w;
    }
#pragma unroll
    for (int hi = 0; hi < 2; ++hi) {
        bf16x8 o0, o1;
#pragma unroll
        for (int r = 0; r < 16; ++r) {
            const int crow = (r & 3) + 8 * (r >> 2) + 4 * hi;
            const short s = f2bs(cf * (0.1f + 0.9f * v[crow]));
            if (r < 8) o0[r] = s; else o1[r - 8] = s;
        }
        short* dst = maskF + ((size_t)(mt * 2 + hi) * N_ + n) * 16;
        *(bf16x8*)dst = o0;
        *(bf16x8*)(dst + 8) = o1;
    }
}

// ---------------------------------------------------------------------------
// Kernel 1: QKV projection (fp32 compute). Writes bf16:
//   q  -> qb  [bh][n][32]               (row-major)
//   k  -> kbF [bh][mt][l5=n&31][hi][16] (A-fragment-major for S^T=K.Q^T)
//   v  -> vbF [bh][mt][l5=d][hi][16]    (A-fragment-major for out^T=V^T.P^T)
// fragment slot s holds k-index hi*4 + (s&3) + 8*(s>>2)
// ---------------------------------------------------------------------------
__global__ __launch_bounds__(256) void qkv_gemm(const float* __restrict__ x,
                                                const float* __restrict__ W,
                                                const float* __restrict__ bias,
                                                short* __restrict__ qb,
                                                short* __restrict__ kbF,
                                                short* __restrict__ vbF) {
    __shared__ float xs[64][68];
    __shared__ float ws[64][68];
    const int t = threadIdx.x;
    const int tx = t & 15, ty = t >> 4;
    const int m0 = blockIdx.y * 64;
    const int j0 = blockIdx.x * 64;
    float acc[4][4] = {};
    for (int k0 = 0; k0 < 256; k0 += 64) {
#pragma unroll
        for (int rep = 0; rep < 4; ++rep) {
            const int row = ty + rep * 16;
            const int c4 = tx * 4;
            *(float4*)&xs[row][c4] =
                *(const float4*)&x[(size_t)(m0 + row) * 256 + k0 + c4];
            *(float4*)&ws[row][c4] =
                *(const float4*)&W[(size_t)(k0 + row) * 768 + j0 + c4];
        }
        __syncthreads();
#pragma unroll
        for (int kk = 0; kk < 64; kk += 4) {
            float4 a[4], b[4];
#pragma unroll
            for (int ii = 0; ii < 4; ++ii) a[ii] = *(float4*)&xs[ty * 4 + ii][kk];
#pragma unroll
            for (int kx = 0; kx < 4; ++kx) b[kx] = *(float4*)&ws[kk + kx][tx * 4];
#pragma unroll
            for (int ii = 0; ii < 4; ++ii) {
                const float av[4] = {a[ii].x, a[ii].y, a[ii].z, a[ii].w};
#pragma unroll
                for (int kx = 0; kx < 4; ++kx) {
                    acc[ii][0] = fmaf(av[kx], b[kx].x, acc[ii][0]);
                    acc[ii][1] = fmaf(av[kx], b[kx].y, acc[ii][1]);
                    acc[ii][2] = fmaf(av[kx], b[kx].z, acc[ii][2]);
                    acc[ii][3] = fmaf(av[kx], b[kx].w, acc[ii][3]);
                }
            }
        }
        __syncthreads();
    }
#pragma unroll
    for (int ii = 0; ii < 4; ++ii) {
        const int gm = m0 + ty * 4 + ii;
        const int bb = gm >> 11, n = gm & 2047;
        const int mt = n >> 5, nl = n & 31;
#pragma unroll
        for (int jj = 0; jj < 4; ++jj) {
            const int c = j0 + tx * 4 + jj;
            const short val = f2bs(acc[ii][jj] + bias[c]);
            const int t3 = c >> 8, rem = c & 255;
            const int h = rem >> 5, dd = rem & 31;
            const size_t bh = (size_t)(bb * H_ + h);
            if (t3 == 0) {
                qb[(bh * N_ + n) * D_ + dd] = val;
            } else if (t3 == 1) {
                const int hi = (dd >> 2) & 1, s = (dd & 3) + 4 * (dd >> 3);
                kbF[((bh * 64 + mt) * 32 + nl) * 32 + hi * 16 + s] = val;
            } else {
                const int hi = (nl >> 2) & 1, s = (nl & 3) + 4 * (nl >> 3);
                vbF[((bh * 64 + mt) * 32 + dd) * 32 + hi * 16 + s] = val;
            }
        }
    }
}

// ---------------------------------------------------------------------------
// Kernel 2: MFMA flash attention, LDS-free main loop.
// Block = 4 waves, one 32-q-row tile of one (b,h). Split-m: wave w handles
// m-tiles [w*16, w*16+16). No max-subtraction -> partial (acc,lsum) just add;
// combined via small LDS reduction at the end.
// ---------------------------------------------------------------------------
__global__ __launch_bounds__(256, 4) void attn_mfma(const short* __restrict__ qb,
                                                    const short* __restrict__ kbF,
                                                    const short* __restrict__ vbF,
                                                    const short* __restrict__ maskF,
                                                    float* __restrict__ ao) {
    __shared__ float red[4][32][33];
    __shared__ float Ls[4][32];
    const int t = threadIdx.x;
    const int w = t >> 6, lane = t & 63, l5 = lane & 31, hi = lane >> 5;
    const int hi4 = hi * 4;
    const int bh = blockIdx.x >> 6, qt = blockIdx.x & 63;
    const int q0 = qt * 32, nq = q0 + l5;

    // Q B-fragments (same for all 4 waves)
    const short* qrow = qb + ((size_t)bh * N_ + nq) * D_;
    const bf16x8 qf0 = __builtin_shufflevector(*(const bf16x4*)(qrow + hi4),
                                               *(const bf16x4*)(qrow + hi4 + 8),
                                               0, 1, 2, 3, 4, 5, 6, 7);
    const bf16x8 qf1 = __builtin_shufflevector(*(const bf16x4*)(qrow + hi4 + 16),
                                               *(const bf16x4*)(qrow + hi4 + 24),
                                               0, 1, 2, 3, 4, 5, 6, 7);
    f32x16 acc;
#pragma unroll
    for (int i = 0; i < 16; ++i) acc[i] = 0.f;
    float lsum = 0.f;

    const size_t fragbase = ((size_t)bh * 64) * 32 * 32;  // per-bh fragment array base
#pragma unroll 2
    for (int i = 0; i < 16; ++i) {
        const int mt = w * 16 + i;
        const short* kp = kbF + fragbase + ((size_t)mt * 32 + l5) * 32 + hi * 16;
        const bf16x8 af0 = *(const bf16x8*)kp;
        const bf16x8 af1 = *(const bf16x8*)(kp + 8);
        f32x16 s;
#pragma unroll
        for (int j = 0; j < 16; ++j) s[j] = 0.f;
        s = __builtin_amdgcn_mfma_f32_32x32x16_bf16(af0, qf0, s, 0, 0, 0);
        s = __builtin_amdgcn_mfma_f32_32x32x16_bf16(af1, qf1, s, 0, 0, 0);

        const short* mp = maskF + ((size_t)(mt * 2 + hi) * N_ + nq) * 16;
        const bf16x8 mf0 = *(const bf16x8*)mp;
        const bf16x8 mf1 = *(const bf16x8*)(mp + 8);
        float p[16];
#pragma unroll
        for (int r = 0; r < 16; ++r) {
            const float fm = b2f(r < 8 ? mf0[r] : mf1[r - 8]);
            p[r] = __builtin_amdgcn_exp2f(s[r] * fm);
            lsum += p[r];
        }
        bf16x8 pf0, pf1;
#pragma unroll
        for (int j = 0; j < 8; ++j) {
            pf0[j] = f2bs(p[j]);
            pf1[j] = f2bs(p[8 + j]);
        }
        const short* vp = vbF + fragbase + ((size_t)mt * 32 + l5) * 32 + hi * 16;
        const bf16x8 vf0 = *(const bf16x8*)vp;
        const bf16x8 vf1 = *(const bf16x8*)(vp + 8);
        acc = __builtin_amdgcn_mfma_f32_32x32x16_bf16(vf0, pf0, acc, 0, 0, 0);
        acc = __builtin_amdgcn_mfma_f32_32x32x16_bf16(vf1, pf1, acc, 0, 0, 0);
    }

    // per-wave partials -> LDS
    const float lt = lsum + __shfl_xor(lsum, 32);
    Ls[w][l5] = lt;  // both hi-lanes write the same value
#pragma unroll
    for (int r = 0; r < 16; ++r) {
        const int d = (r & 3) + 8 * (r >> 2) + hi4;
        red[w][d][l5] = acc[r];
    }
    __syncthreads();

    // combine 4 wave-partials; thread t handles (q = t>>3, d4 = (t&7)*4)
    const int q = t >> 3, d4 = (t & 7) * 4;
    const float inv = 1.0f / (Ls[0][q] + Ls[1][q] + Ls[2][q] + Ls[3][q]);
    float4 o;
    float* op = &o.x;
#pragma unroll
    for (int j = 0; j < 4; ++j) {
        op[j] = (red[0][d4 + j][q] + red[1][d4 + j][q] +
                 red[2][d4 + j][q] + red[3][d4 + j][q]) * inv;
    }
    const int bb = bh >> 3, h = bh & 7;
    *(float4*)(ao + (size_t)(bb * N_ + q0 + q) * C_ + h * D_ + d4) = o;
}

// ---------------------------------------------------------------------------
// Kernel 3: output projection (fp32). out = ao @ W_out + b_out.
// ---------------------------------------------------------------------------
__global__ __launch_bounds__(256) void out_gemm(const float* __restrict__ xin,
                                                const float* __restrict__ W,
                                                const float* __restrict__ bias,
                                                float* __restrict__ out) {
    __shared__ float xs[64][68];
    __shared__ float ws[64][68];
    const int t = threadIdx.x;
    const int tx = t & 15, ty = t >> 4;
    const int m0 = blockIdx.y * 64;
    const int j0 = blockIdx.x * 64;
    float acc[4][4] = {};
    for (int k0 = 0; k0 < 256; k0 += 64) {
#pragma unroll
        for (int rep = 0; rep < 4; ++rep) {
            const int row = ty + rep * 16;
            const int c4 = tx * 4;
            *(float4*)&xs[row][c4] =
                *(const float4*)&xin[(size_t)(m0 + row) * 256 + k0 + c4];
            *(float4*)&ws[row][c4] =
                *(const float4*)&W[(size_t)(k0 + row) * 256 + j0 + c4];
        }
        __syncthreads();
#pragma unroll
        for (int kk = 0; kk < 64; kk += 4) {
            float4 a[4], b[4];
#pragma unroll
            for (int ii = 0; ii < 4; ++ii) a[ii] = *(float4*)&xs[ty * 4 + ii][kk];
#pragma unroll
            for (int kx = 0; kx < 4; ++kx) b[kx] = *(float4*)&ws[kk + kx][tx * 4];
#pragma unroll
            for (int ii = 0; ii < 4; ++ii) {
                const float av[4] = {a[ii].x, a[ii].y, a[ii].z, a[ii].w};
#pragma unroll
                for (int kx = 0; kx < 4; ++kx) {
                    acc[ii][0] = fmaf(av[kx], b[kx].x, acc[ii][0]);
                    acc[ii][1] = fmaf(av[kx], b[kx].y, acc[ii][1]);
                    acc[ii][2] = fmaf(av[kx], b[kx].z, acc[ii][2]);
                    acc[ii][3] = fmaf(av[kx], b[kx].w, acc[ii][3]);
                }
            }
        }
        __syncthreads();
    }
#pragma unroll
    for (int ii = 0; ii < 4; ++ii) {
        const int gm = m0 + ty * 4 + ii;
#pragma unroll
        for (int jj = 0; jj < 4; ++jj) {
            const int c = j0 + tx * 4 + jj;
            out[(size_t)gm * 256 + c] = acc[ii][jj] + bias[c];
        }
    }
}

extern "C" void kernel_launch(void* const* d_in, const int* in_sizes, int n_in,
                              void* d_out, int out_size, void* d_ws, size_t ws_size,
                              hipStream_t stream) {
    const float* x = (const float*)d_in[0];
    const float* mask = (const float*)d_in[1];
    const float* W_qkv = (const float*)d_in[2];
    const float* b_qkv = (const float*)d_in[3];
    const float* W_out = (const float*)d_in[4];
    const float* b_out = (const float*)d_in[5];
    float* out = (float*)d_out;

    const size_t per = (size_t)B_ * H_ * N_ * D_;  // 2,097,152 elems
    short* qb = (short*)d_ws;
    short* kbF = qb + per;
    short* vbF = kbF + per;
    short* maskF = vbF + per;                       // N*N shorts = 8MB
    float* ao = (float*)(maskF + (size_t)N_ * N_);  // 2,097,152 floats

    mask_relayout<<<dim3(16, 32), 256, 0, stream>>>(mask, maskF);
    qkv_gemm<<<dim3(12, 128), 256, 0, stream>>>(x, W_qkv, b_qkv, qb, kbF, vbF);
    attn_mfma<<<dim3(2048), 256, 0, stream>>>(qb, kbF, vbF, maskF, ao);
    out_gemm<<<dim3(4, 128), 256, 0, stream>>>(ao, W_out, b_out, out);
}

// Round 4
// 79.476 us; speedup vs baseline: 17.6605x; 1.6376x over previous
//
#include <hip/hip_runtime.h>
#include <hip/hip_bf16.h>

#define B_ 4
#define N_ 2048
#define C_ 256
#define H_ 8
#define D_ 32

typedef __attribute__((ext_vector_type(4))) short bf16x4;
typedef __attribute__((ext_vector_type(8))) short bf16x8;
typedef __attribute__((ext_vector_type(16))) float f32x16;

static __device__ __forceinline__ float b2f(short u) {
    unsigned v = ((unsigned)(unsigned short)u) << 16;
    return __builtin_bit_cast(float, v);
}
static __device__ __forceinline__ short f2bs(float f) {
    __hip_bfloat16 h = __float2bfloat16(f);
    return __builtin_bit_cast(short, h);
}

// Fragment k-map (32x32x16 bf16, verified in R2/R3): slot s (0..15), lane-half hi:
//   element index dd = hi*4 + (s&3) + 8*(s>>2)   (dd in 0..31, per 32-k chunk)
// Inverse: hi = (dd>>2)&1, s = (dd&3) + 4*(dd>>3)
// Frag arrays: F[((tile*8 + kt32)*32 + l5)*32 + hi*16 + s], 32B per lane per kt32.

// ---------------------------------------------------------------------------
// x relayout: fp32 [8192][256] -> bf16 A-fragment-major
// ---------------------------------------------------------------------------
__global__ __launch_bounds__(256) void x_relayout(const float* __restrict__ x,
                                                  short* __restrict__ xF) {
    const int idx = blockIdx.x * 256 + threadIdx.x;  // f4 index
    const int row = idx >> 6, c0 = (idx & 63) * 4;
    const float4 f4 = *(const float4*)(x + (size_t)row * 256 + c0);
    const int mt = row >> 5, l5 = row & 31;
    const int kt = c0 >> 5, dd0 = c0 & 31;
    const int hi = (dd0 >> 2) & 1, s0 = 4 * (dd0 >> 3);
    bf16x4 o;
    o[0] = f2bs(f4.x); o[1] = f2bs(f4.y); o[2] = f2bs(f4.z); o[3] = f2bs(f4.w);
    *(bf16x4*)(xF + (((size_t)mt * 8 + kt) * 32 + l5) * 32 + hi * 16 + s0) = o;
}

// ---------------------------------------------------------------------------
// W relayout (both W_qkv 256x768 and W_out 256x256) -> bf16 B-fragment-major
// ---------------------------------------------------------------------------
__global__ __launch_bounds__(256) void w_relayout(const float* __restrict__ Wq,
                                                  const float* __restrict__ Wo,
                                                  short* __restrict__ wqF,
                                                  short* __restrict__ woF) {
    int idx = blockIdx.x * 256 + threadIdx.x;
    const float* W; short* dst; int ncols;
    if (idx < 49152) { W = Wq; dst = wqF; ncols = 768; }
    else { idx -= 49152; W = Wo; dst = woF; ncols = 256; }
    const int f4pr = ncols >> 2;
    const int row = idx / f4pr, c0 = (idx % f4pr) * 4;
    const float4 f4 = *(const float4*)(W + (size_t)row * ncols + c0);
    const int kt = row >> 5, dd = row & 31;
    const int hi = (dd >> 2) & 1, s = (dd & 3) + 4 * (dd >> 3);
    const float vals[4] = {f4.x, f4.y, f4.z, f4.w};
#pragma unroll
    for (int j = 0; j < 4; ++j) {
        const int col = c0 + j, nt = col >> 5, l5 = col & 31;
        dst[(((size_t)nt * 8 + kt) * 32 + l5) * 32 + hi * 16 + s] = f2bs(vals[j]);
    }
}

// ---------------------------------------------------------------------------
// mask relayout into MFMA C-fragment order, premultiplied with scale*log2e
// ---------------------------------------------------------------------------
__global__ __launch_bounds__(256) void mask_relayout(const float* __restrict__ mask,
                                                     short* __restrict__ maskF) {
    const int t = threadIdx.x;
    const int n = blockIdx.y * 64 + (t & 63);
    const int mt = blockIdx.x * 4 + (t >> 6);
    const float cf = 0.17677669529663687f * 1.4426950408889634f;
    float v[32];
    const float4* src = (const float4*)(mask + (size_t)n * N_ + mt * 32);
#pragma unroll
    for (int i = 0; i < 8; ++i) {
        const float4 f4 = src[i];
        v[i * 4 + 0] = f4.x; v[i * 4 + 1] = f4.y;
        v[i * 4 + 2] = f4.z; v[i * 4 + 3] = f4.w;
    }
#pragma unroll
    for (int hi = 0; hi < 2; ++hi) {
        bf16x8 o0, o1;
#pragma unroll
        for (int r = 0; r < 16; ++r) {
            const int crow = (r & 3) + 8 * (r >> 2) + 4 * hi;
            const short s = f2bs(cf * (0.1f + 0.9f * v[crow]));
            if (r < 8) o0[r] = s; else o1[r - 8] = s;
        }
        short* dst = maskF + ((size_t)(mt * 2 + hi) * N_ + n) * 16;
        *(bf16x8*)dst = o0;
        *(bf16x8*)(dst + 8) = o1;
    }
}

// ---------------------------------------------------------------------------
// QKV projection, MFMA. Wave = one 32x32 tile (m-tile x channel-tile).
// Channel-tile nt: 0-7 => q head nt; 8-15 => k head nt-8; 16-23 => v head.
// Epilogue: per-wave LDS transpose, scatter q row-major / k,v fragment-major.
// ---------------------------------------------------------------------------
__global__ __launch_bounds__(256, 4) void qkv_mfma(const short* __restrict__ xF,
                                                   const short* __restrict__ wqF,
                                                   const float* __restrict__ bias,
                                                   short* __restrict__ qb,
                                                   short* __restrict__ kbF,
                                                   short* __restrict__ vbF) {
    __shared__ short sc[4][32 * 34];
    const int t = threadIdx.x;
    const int w = t >> 6, lane = t & 63, l5 = lane & 31, hi = lane >> 5;
    const int tile = blockIdx.x * 4 + w;
    const int nt = tile % 24, mt = tile / 24;
    f32x16 acc;
#pragma unroll
    for (int i = 0; i < 16; ++i) acc[i] = 0.f;
    const short* ap = xF + ((size_t)mt * 8 * 32) * 32 + l5 * 32 + hi * 16;
    const short* bp = wqF + ((size_t)nt * 8 * 32) * 32 + l5 * 32 + hi * 16;
#pragma unroll
    for (int kt = 0; kt < 8; ++kt) {
        const bf16x8 a0 = *(const bf16x8*)(ap + kt * 1024);
        const bf16x8 a1 = *(const bf16x8*)(ap + kt * 1024 + 8);
        const bf16x8 b0 = *(const bf16x8*)(bp + kt * 1024);
        const bf16x8 b1 = *(const bf16x8*)(bp + kt * 1024 + 8);
        acc = __builtin_amdgcn_mfma_f32_32x32x16_bf16(a0, b0, acc, 0, 0, 0);
        acc = __builtin_amdgcn_mfma_f32_32x32x16_bf16(a1, b1, acc, 0, 0, 0);
    }
    const float bq = bias[nt * 32 + l5];
    short* myc = sc[w];
#pragma unroll
    for (int r = 0; r < 16; ++r)
        myc[((r & 3) + 8 * (r >> 2) + 4 * hi) * 34 + l5] = f2bs(acc[r] + bq);
    __syncthreads();

    const int h = nt & 7, t3 = nt >> 3;
    const int mtk = mt & 63;
    const size_t bh = (size_t)(mt >> 6) * 8 + h;
    if (t3 == 0) {
        // q row-major: lane (row=l5, half=hi) -> 16 channels
        const bf16x8 r0 = *(const bf16x8*)(myc + l5 * 34 + hi * 16);
        const bf16x8 r1 = *(const bf16x8*)(myc + l5 * 34 + hi * 16 + 8);
        short* dst = qb + (bh * N_ + (size_t)mtk * 32 + l5) * D_ + hi * 16;
        *(bf16x8*)dst = r0;
        *(bf16x8*)(dst + 8) = r1;
    } else if (t3 == 1) {
        // k fragment-major: lane (nl=l5, half=hi): slot s <- channel dd(hi,s)
        bf16x8 o0, o1;
#pragma unroll
        for (int s = 0; s < 16; ++s) {
            const int dd = hi * 4 + (s & 3) + 8 * (s >> 2);
            const short vv = myc[l5 * 34 + dd];
            if (s < 8) o0[s] = vv; else o1[s - 8] = vv;
        }
        short* dst = kbF + ((bh * 64 + mtk) * 32 + l5) * 32 + hi * 16;
        *(bf16x8*)dst = o0;
        *(bf16x8*)(dst + 8) = o1;
    } else {
        // v fragment-major: lane (dd=l5, half=hi): slot s <- seq-row nl(hi,s)
        bf16x8 o0, o1;
#pragma unroll
        for (int s = 0; s < 16; ++s) {
            const int nl = hi * 4 + (s & 3) + 8 * (s >> 2);
            const short vv = myc[nl * 34 + l5];
            if (s < 8) o0[s] = vv; else o1[s - 8] = vv;
        }
        short* dst = vbF + ((bh * 64 + mtk) * 32 + l5) * 32 + hi * 16;
        *(bf16x8*)dst = o0;
        *(bf16x8*)(dst + 8) = o1;
    }
}

// ---------------------------------------------------------------------------
// MFMA flash attention. Block = 4 waves (split-m x4), 64 q-rows (2 q-tiles
// sharing K/V fragments -> 2x ILP, half K/V traffic). Output written directly
// in A-fragment layout for the out-projection GEMM (channel-tile == head).
// ---------------------------------------------------------------------------
__global__ __launch_bounds__(256, 4) void attn_mfma(const short* __restrict__ qb,
                                                    const short* __restrict__ kbF,
                                                    const short* __restrict__ vbF,
                                                    const short* __restrict__ maskF,
                                                    short* __restrict__ aoF) {
    __shared__ float red[4][32][33];
    __shared__ float Ls[4][32];
    const int t = threadIdx.x;
    const int w = t >> 6, lane = t & 63, l5 = lane & 31, hi = lane >> 5;
    const int hi4 = hi * 4;
    const int bh = blockIdx.x >> 5, qg = blockIdx.x & 31;
    const int q0 = qg * 64;
    const int nqA = q0 + l5, nqB = q0 + 32 + l5;

    const short* qrA = qb + ((size_t)bh * N_ + nqA) * D_;
    const short* qrB = qb + ((size_t)bh * N_ + nqB) * D_;
    const bf16x8 qfA0 = __builtin_shufflevector(*(const bf16x4*)(qrA + hi4),
                                                *(const bf16x4*)(qrA + hi4 + 8),
                                                0, 1, 2, 3, 4, 5, 6, 7);
    const bf16x8 qfA1 = __builtin_shufflevector(*(const bf16x4*)(qrA + hi4 + 16),
                                                *(const bf16x4*)(qrA + hi4 + 24),
                                                0, 1, 2, 3, 4, 5, 6, 7);
    const bf16x8 qfB0 = __builtin_shufflevector(*(const bf16x4*)(qrB + hi4),
                                                *(const bf16x4*)(qrB + hi4 + 8),
                                                0, 1, 2, 3, 4, 5, 6, 7);
    const bf16x8 qfB1 = __builtin_shufflevector(*(const bf16x4*)(qrB + hi4 + 16),
                                                *(const bf16x4*)(qrB + hi4 + 24),
                                                0, 1, 2, 3, 4, 5, 6, 7);
    f32x16 accA, accB;
#pragma unroll
    for (int i = 0; i < 16; ++i) { accA[i] = 0.f; accB[i] = 0.f; }
    float lsA = 0.f, lsB = 0.f;

    const size_t fragbase = (size_t)bh * 64 * 1024;
#pragma unroll 4
    for (int i = 0; i < 16; ++i) {
        const int mt = w * 16 + i;
        const short* kp = kbF + fragbase + (size_t)mt * 1024 + l5 * 32 + hi * 16;
        const bf16x8 af0 = *(const bf16x8*)kp;
        const bf16x8 af1 = *(const bf16x8*)(kp + 8);
        f32x16 sA, sB;
#pragma unroll
        for (int j = 0; j < 16; ++j) { sA[j] = 0.f; sB[j] = 0.f; }
        sA = __builtin_amdgcn_mfma_f32_32x32x16_bf16(af0, qfA0, sA, 0, 0, 0);
        sA = __builtin_amdgcn_mfma_f32_32x32x16_bf16(af1, qfA1, sA, 0, 0, 0);
        sB = __builtin_amdgcn_mfma_f32_32x32x16_bf16(af0, qfB0, sB, 0, 0, 0);
        sB = __builtin_amdgcn_mfma_f32_32x32x16_bf16(af1, qfB1, sB, 0, 0, 0);

        const short* mpA = maskF + ((size_t)(mt * 2 + hi) * N_ + nqA) * 16;
        const short* mpB = maskF + ((size_t)(mt * 2 + hi) * N_ + nqB) * 16;
        const bf16x8 mA0 = *(const bf16x8*)mpA;
        const bf16x8 mA1 = *(const bf16x8*)(mpA + 8);
        const bf16x8 mB0 = *(const bf16x8*)mpB;
        const bf16x8 mB1 = *(const bf16x8*)(mpB + 8);

        bf16x8 pfA0, pfA1, pfB0, pfB1;
#pragma unroll
        for (int r = 0; r < 16; ++r) {
            const float fmA = b2f(r < 8 ? mA0[r] : mA1[r - 8]);
            const float fmB = b2f(r < 8 ? mB0[r] : mB1[r - 8]);
            const float pA = __builtin_amdgcn_exp2f(sA[r] * fmA);
            const float pB = __builtin_amdgcn_exp2f(sB[r] * fmB);
            lsA += pA; lsB += pB;
            const short hA = f2bs(pA), hB = f2bs(pB);
            if (r < 8) { pfA0[r] = hA; pfB0[r] = hB; }
            else       { pfA1[r - 8] = hA; pfB1[r - 8] = hB; }
        }
        const short* vp = vbF + fragbase + (size_t)mt * 1024 + l5 * 32 + hi * 16;
        const bf16x8 vf0 = *(const bf16x8*)vp;
        const bf16x8 vf1 = *(const bf16x8*)(vp + 8);
        accA = __builtin_amdgcn_mfma_f32_32x32x16_bf16(vf0, pfA0, accA, 0, 0, 0);
        accA = __builtin_amdgcn_mfma_f32_32x32x16_bf16(vf1, pfA1, accA, 0, 0, 0);
        accB = __builtin_amdgcn_mfma_f32_32x32x16_bf16(vf0, pfB0, accB, 0, 0, 0);
        accB = __builtin_amdgcn_mfma_f32_32x32x16_bf16(vf1, pfB1, accB, 0, 0, 0);
    }

    // two reduction rounds (one per q-tile), reusing the same LDS buffer
    const int h = bh & 7;
    const int gmtb = (bh >> 3) * 64 + qg * 2;
#pragma unroll
    for (int tq = 0; tq < 2; ++tq) {
        if (tq) __syncthreads();
        const float lsum = tq ? lsB : lsA;
        const f32x16 acc = tq ? accB : accA;
        const float lt = lsum + __shfl_xor(lsum, 32);
        Ls[w][l5] = lt;
#pragma unroll
        for (int r = 0; r < 16; ++r)
            red[w][(r & 3) + 8 * (r >> 2) + hi4][l5] = acc[r];
        __syncthreads();
        // reduce: thread -> (row = t&31, hi2 = (t>>5)&1, sh = t>>6)
        const int row = t & 31, hi2 = (t >> 5) & 1, sh = t >> 6;
        const float inv = 1.0f / (Ls[0][row] + Ls[1][row] + Ls[2][row] + Ls[3][row]);
        bf16x4 o;
#pragma unroll
        for (int j = 0; j < 4; ++j) {
            const int dd = hi2 * 4 + j + 8 * sh;
            o[j] = f2bs((red[0][dd][row] + red[1][dd][row] +
                         red[2][dd][row] + red[3][dd][row]) * inv);
        }
        const size_t gmt = gmtb + tq;
        *(bf16x4*)(aoF + ((gmt * 8 + h) * 32 + row) * 32 + hi2 * 16 + sh * 4) = o;
    }
}

// ---------------------------------------------------------------------------
// Output projection, MFMA: out = ao @ W_out + b_out (fp32 out, direct stores)
// ---------------------------------------------------------------------------
__global__ __launch_bounds__(256, 4) void out_mfma(const short* __restrict__ aoF,
                                                   const short* __restrict__ woF,
                                                   const float* __restrict__ bias,
                                                   float* __restrict__ out) {
    const int t = threadIdx.x;
    const int w = t >> 6, lane = t & 63, l5 = lane & 31, hi = lane >> 5;
    const int tile = blockIdx.x * 4 + w;
    const int nt = tile & 7, mt = tile >> 3;
    f32x16 acc;
#pragma unroll
    for (int i = 0; i < 16; ++i) acc[i] = 0.f;
    const short* ap = aoF + (size_t)mt * 8192 + l5 * 32 + hi * 16;
    const short* bp = woF + (size_t)nt * 8192 + l5 * 32 + hi * 16;
#pragma unroll
    for (int kt = 0; kt < 8; ++kt) {
        const bf16x8 a0 = *(const bf16x8*)(ap + kt * 1024);
        const bf16x8 a1 = *(const bf16x8*)(ap + kt * 1024 + 8);
        const bf16x8 b0 = *(const bf16x8*)(bp + kt * 1024);
        const bf16x8 b1 = *(const bf16x8*)(bp + kt * 1024 + 8);
        acc = __builtin_amdgcn_mfma_f32_32x32x16_bf16(a0, b0, acc, 0, 0, 0);
        acc = __builtin_amdgcn_mfma_f32_32x32x16_bf16(a1, b1, acc, 0, 0, 0);
    }
    const float bo = bias[nt * 32 + l5];
#pragma unroll
    for (int r = 0; r < 16; ++r) {
        const int crow = (r & 3) + 8 * (r >> 2) + 4 * hi;
        out[(size_t)(mt * 32 + crow) * 256 + nt * 32 + l5] = acc[r] + bo;
    }
}

extern "C" void kernel_launch(void* const* d_in, const int* in_sizes, int n_in,
                              void* d_out, int out_size, void* d_ws, size_t ws_size,
                              hipStream_t stream) {
    const float* x = (const float*)d_in[0];
    const float* mask = (const float*)d_in[1];
    const float* W_qkv = (const float*)d_in[2];
    const float* b_qkv = (const float*)d_in[3];
    const float* W_out = (const float*)d_in[4];
    const float* b_out = (const float*)d_in[5];
    float* out = (float*)d_out;

    const size_t per = (size_t)B_ * H_ * N_ * D_;  // 2,097,152
    short* qb = (short*)d_ws;
    short* kbF = qb + per;
    short* vbF = kbF + per;
    short* maskF = vbF + per;            // N*N = 4,194,304 shorts
    short* xF = maskF + (size_t)N_ * N_; // 2,097,152 shorts
    short* wqF = xF + per;               // 196,608 shorts
    short* woF = wqF + 196608;           // 65,536 shorts
    short* aoF = xF;                     // reuse xF (consumed by qkv_mfma)

    x_relayout<<<2048, 256, 0, stream>>>(x, xF);
    w_relayout<<<256, 256, 0, stream>>>(W_qkv, W_out, wqF, woF);
    mask_relayout<<<dim3(16, 32), 256, 0, stream>>>(mask, maskF);
    qkv_mfma<<<1536, 256, 0, stream>>>(xF, wqF, b_qkv, qb, kbF, vbF);
    attn_mfma<<<1024, 256, 0, stream>>>(qb, kbF, vbF, maskF, aoF);
    out_mfma<<<512, 256, 0, stream>>>(aoF, woF, b_out, out);
}